// Round 3
// baseline (647.534 us; speedup 1.0000x reference)
//
#include <hip/hip_runtime.h>
#include <stdint.h>

typedef unsigned short u16;
typedef float f32x4 __attribute__((ext_vector_type(4)));
typedef __bf16 bf16x8 __attribute__((ext_vector_type(8)));

__device__ __forceinline__ float b2f(u16 u) {
    union { unsigned int i; float f; } w; w.i = ((unsigned int)u) << 16; return w.f;
}
__device__ __forceinline__ u16 f2b(float f) {
    union { float f; unsigned int i; } w; w.f = f;
    unsigned int r = w.i + 0x7fffu + ((w.i >> 16) & 1u);
    return (u16)(r >> 16);
}

// ---------------- transpose+cast weights: W[k][n] fp32 (1024x1024) -> Wt[n][k] bf16 ----------------
__global__ __launch_bounds__(256) void transpose_w(
    const float* __restrict__ Wq, const float* __restrict__ Wk, const float* __restrict__ Wv,
    const float* __restrict__ Wo, u16* __restrict__ WqkvT, u16* __restrict__ WoT)
{
    const float* src = (blockIdx.z == 0) ? Wq : (blockIdx.z == 1) ? Wk : (blockIdx.z == 2) ? Wv : Wo;
    u16* dst = (blockIdx.z < 3) ? (WqkvT + (size_t)blockIdx.z * 1024 * 1024) : WoT;
    __shared__ u16 tile[32][33];
    int tx = threadIdx.x & 31, ty = threadIdx.x >> 5;  // 32 x 8
    int n0 = blockIdx.x * 32, k0 = blockIdx.y * 32;
#pragma unroll
    for (int i = 0; i < 4; i++) tile[ty + 8 * i][tx] = f2b(src[(size_t)(k0 + ty + 8 * i) * 1024 + n0 + tx]);
    __syncthreads();
#pragma unroll
    for (int i = 0; i < 4; i++) dst[(size_t)(n0 + ty + 8 * i) * 1024 + k0 + tx] = tile[tx][ty + 8 * i];
}

// ---------------- pack biases fp32: [bq|bk|bv|out_b] = 4096 ----------------
__global__ __launch_bounds__(256) void pack_bias(
    const float* __restrict__ bq, const float* __restrict__ bk, const float* __restrict__ bv,
    const float* __restrict__ ob, float* __restrict__ biasAll)
{
    int i = blockIdx.x * 256 + threadIdx.x;
    float v;
    if (i < 1024) v = bq[i];
    else if (i < 2048) v = bk[i - 1024];
    else if (i < 3072) v = bv[i - 2048];
    else v = ob[i - 3072];
    biasAll[i] = v;
}

// ---------------- LayerNorm(x fp32) -> xn (bf16), one row per block ----------------
__global__ __launch_bounds__(256) void ln_x(
    const float* __restrict__ x, const float* __restrict__ g, const float* __restrict__ bt,
    u16* __restrict__ xn)
{
    int row = blockIdx.x, tid = threadIdx.x;
    const float* xr = x + (size_t)row * 1024;
    float4 u = *(const float4*)(xr + tid * 4);
    float v0 = u.x, v1 = u.y, v2 = u.z, v3 = u.w;
    float s = v0 + v1 + v2 + v3;
    float s2 = v0 * v0 + v1 * v1 + v2 * v2 + v3 * v3;
#pragma unroll
    for (int m = 32; m > 0; m >>= 1) { s += __shfl_xor(s, m, 64); s2 += __shfl_xor(s2, m, 64); }
    __shared__ float red[8];
    int w = tid >> 6, lane = tid & 63;
    if (lane == 0) { red[w] = s; red[4 + w] = s2; }
    __syncthreads();
    s = red[0] + red[1] + red[2] + red[3];
    s2 = red[4] + red[5] + red[6] + red[7];
    float mean = s * (1.f / 1024.f);
    float var = s2 * (1.f / 1024.f) - mean * mean;
    float rstd = rsqrtf(var + 1e-5f);
    int c = tid * 4;
    float4 gg = *(const float4*)(g + c);
    float4 bb = *(const float4*)(bt + c);
    ushort4 o;
    o.x = f2b((v0 - mean) * rstd * gg.x + bb.x);
    o.y = f2b((v1 - mean) * rstd * gg.y + bb.y);
    o.z = f2b((v2 - mean) * rstd * gg.z + bb.z);
    o.w = f2b((v3 - mean) * rstd * gg.w + bb.w);
    *(ushort4*)(xn + (size_t)row * 1024 + c) = o;
}

// ---------------- 128x128 MFMA GEMM (K=1024), A[M,K] bf16 row-major, Bt[N,K] bf16 ----------------
// epi==0: Cb = bf16(A@B + bias), stride ldc
// epi==1: Cf = Xf + gate * (A@B + bias)  (all fp32)
__global__ __launch_bounds__(256) void gemm128(
    const u16* __restrict__ A, const u16* __restrict__ Bt, const float* __restrict__ bias,
    u16* __restrict__ Cb, float* __restrict__ Cf, int ldc, int epi,
    const float* __restrict__ Xf, const float* __restrict__ gate)
{
    const int K = 1024;
    __shared__ __align__(16) u16 As[128 * 64];
    __shared__ __align__(16) u16 Bs[128 * 64];
    int tid = threadIdx.x, lane = tid & 63, w = tid >> 6;
    int wm = w >> 1, wn = w & 1;
    size_t rowbase = (size_t)blockIdx.y * 128;
    size_t colbase = (size_t)blockIdx.x * 128;
    const u16* Ab = A + rowbase * K;
    const u16* Bb = Bt + colbase * K;
    f32x4 acc[4][4] = {};
    int quad = lane >> 4, mr = lane & 15;
    int sr = tid >> 3;          // 0..31
    int sc = (tid & 7) * 8;     // 0..56
    for (int k0 = 0; k0 < K; k0 += 64) {
#pragma unroll
        for (int p = 0; p < 4; p++) {
            int r = p * 32 + sr;
            uint4 av = *(const uint4*)&Ab[(size_t)r * K + k0 + sc];
            uint4 bv = *(const uint4*)&Bb[(size_t)r * K + k0 + sc];
            *(uint4*)&As[r * 64 + sc] = av;
            *(uint4*)&Bs[r * 64 + sc] = bv;
        }
        __syncthreads();
#pragma unroll
        for (int kk = 0; kk < 64; kk += 32) {
            bf16x8 a[4], bf[4];
#pragma unroll
            for (int i = 0; i < 4; i++) a[i] = *(const bf16x8*)&As[(wm * 64 + i * 16 + mr) * 64 + kk + quad * 8];
#pragma unroll
            for (int j = 0; j < 4; j++) bf[j] = *(const bf16x8*)&Bs[(wn * 64 + j * 16 + mr) * 64 + kk + quad * 8];
#pragma unroll
            for (int i = 0; i < 4; i++)
#pragma unroll
                for (int j = 0; j < 4; j++)
                    acc[i][j] = __builtin_amdgcn_mfma_f32_16x16x32_bf16(a[i], bf[j], acc[i][j], 0, 0, 0);
        }
        __syncthreads();
    }
#pragma unroll
    for (int j = 0; j < 4; j++) {
        int col = (int)colbase + wn * 64 + j * 16 + mr;
        float bv_ = bias[col];
#pragma unroll
        for (int i = 0; i < 4; i++) {
#pragma unroll
            for (int r = 0; r < 4; r++) {
                size_t row = rowbase + wm * 64 + i * 16 + quad * 4 + r;
                float v = acc[i][j][r] + bv_;
                if (epi) {
                    int b_ = (int)(row >> 12);
                    Cf[row * (size_t)ldc + col] = Xf[row * (size_t)ldc + col] + gate[b_ * 1024 + col] * v;
                } else {
                    Cb[row * (size_t)ldc + col] = f2b(v);
                }
            }
        }
    }
}

// ---------------- q softmax over dh=64 (one wave per (row,head)), in place, stride 1024 ----------------
__global__ __launch_bounds__(256) void qsoftmax(u16* __restrict__ q)
{
    int idx = blockIdx.x * 4 + (threadIdx.x >> 6);
    int lane = threadIdx.x & 63;
    size_t row = (size_t)(idx >> 4);
    int head = idx & 15;
    u16* p = q + row * 1024 + head * 64 + lane;
    float v = b2f(*p);
    float m = v;
#pragma unroll
    for (int s = 32; s > 0; s >>= 1) m = fmaxf(m, __shfl_xor(m, s, 64));
    float e = __expf(v - m);
    float ss = e;
#pragma unroll
    for (int s = 32; s > 0; s >>= 1) ss += __shfl_xor(ss, s, 64);
    *p = f2b(e / ss);
}

// ---------------- temporal k softmax: pass 1 column sums of exp (stride 1024) ----------------
__global__ __launch_bounds__(256) void ksum(const u16* __restrict__ k, float* __restrict__ colsum)
{
    int c = blockIdx.x * 256 + threadIdx.x;
    int b = blockIdx.z, ch = blockIdx.y;  // 16 chunks x 256 rows
    const u16* p = k + ((size_t)b * 4096 + ch * 256) * 1024 + c;
    float s = 0.f;
#pragma unroll 4
    for (int t = 0; t < 256; t++) s += __expf(b2f(p[(size_t)t * 1024]));
    atomicAdd(&colsum[b * 1024 + c], s);
}

// ---------------- temporal k softmax: pass 2 normalize in place ----------------
__global__ __launch_bounds__(256) void knorm(u16* __restrict__ k, const float* __restrict__ colsum)
{
    int c = blockIdx.x * 256 + threadIdx.x;
    int b = blockIdx.z, ch = blockIdx.y;
    float inv = 1.f / colsum[b * 1024 + c];
    u16* p = k + ((size_t)b * 4096 + ch * 256) * 1024 + c;
#pragma unroll 4
    for (int t = 0; t < 256; t++) { size_t o = (size_t)t * 1024; p[o] = f2b(__expf(b2f(p[o])) * inv); }
}

// ---------------- ctx[b,h] = Ksoft^T V (64x64), T split in 8 chunks, atomicAdd fp32 ----------------
__global__ __launch_bounds__(256) void ctx_k(
    const u16* __restrict__ kbuf, const u16* __restrict__ vbuf, float* __restrict__ ctx)
{
    int ch = blockIdx.x, h = blockIdx.y, b = blockIdx.z;
    __shared__ __align__(16) float Es[16][64];
    __shared__ __align__(16) float Vs[16][64];
    int tid = threadIdx.x;
    int td = tid >> 4, tl = tid & 15;
    float acc[4][4] = {};
    size_t rowbase = (size_t)b * 4096 + ch * 512;
    for (int g = 0; g < 32; ++g) {
#pragma unroll
        for (int rep = 0; rep < 4; ++rep) {
            int e = tid + rep * 256;
            int r = e >> 6, cc = e & 63;
            size_t base = (rowbase + g * 16 + r) * 1024 + h * 64 + cc;
            Es[r][cc] = b2f(kbuf[base]);
            Vs[r][cc] = b2f(vbuf[base]);
        }
        __syncthreads();
#pragma unroll
        for (int n = 0; n < 16; n++) {
            f32x4 e4 = *(const f32x4*)&Es[n][td * 4];
            f32x4 v4 = *(const f32x4*)&Vs[n][tl * 4];
#pragma unroll
            for (int i = 0; i < 4; i++)
#pragma unroll
                for (int j = 0; j < 4; j++) acc[i][j] += e4[i] * v4[j];
        }
        __syncthreads();
    }
    float* cb = ctx + (size_t)(b * 16 + h) * 4096;
#pragma unroll
    for (int i = 0; i < 4; i++)
#pragma unroll
        for (int j = 0; j < 4; j++)
            atomicAdd(&cb[(td * 4 + i) * 64 + tl * 4 + j], acc[i][j]);
}

// ---------------- emb_out = silu(emb) @ emb_W (fp32 in, atomic accumulate over k chunks) ----------------
__global__ __launch_bounds__(256) void embout_k(
    const float* __restrict__ emb, const float* __restrict__ embW, float* __restrict__ eo)
{
    int cb = blockIdx.x, kc = blockIdx.y;  // 8 col-blocks of 256, 8 k-chunks of 128
    __shared__ float semb[512];
    int tid = threadIdx.x;
#pragma unroll
    for (int i = 0; i < 2; i++) {
        int e = tid + i * 256;
        int b = e >> 7, kk = e & 127;
        float xv = emb[b * 1024 + kc * 128 + kk];
        semb[e] = xv / (1.f + __expf(-xv));
    }
    __syncthreads();
    int o = cb * 256 + tid;
    float a0 = 0, a1 = 0, a2 = 0, a3 = 0;
    for (int kk = 0; kk < 128; kk++) {
        float wv = embW[(size_t)(kc * 128 + kk) * 2048 + o];
        a0 += semb[kk] * wv; a1 += semb[128 + kk] * wv;
        a2 += semb[256 + kk] * wv; a3 += semb[384 + kk] * wv;
    }
    atomicAdd(&eo[o], a0);
    atomicAdd(&eo[2048 + o], a1);
    atomicAdd(&eo[4096 + o], a2);
    atomicAdd(&eo[6144 + o], a3);
}

// ---------------- y = q_soft @ ctx per head (MFMA, K=64), q stride 1024, writes y bf16 ----------------
__global__ __launch_bounds__(256) void y_k(
    const u16* __restrict__ q, const float* __restrict__ ctx, u16* __restrict__ y)
{
    int mc = blockIdx.x, h = blockIdx.y, b = blockIdx.z;
    __shared__ __align__(16) u16 Qs[128 * 64];
    __shared__ __align__(16) u16 Cs[64 * 72];
    int tid = threadIdx.x, lane = tid & 63, w = tid >> 6;
    size_t row0 = (size_t)b * 4096 + (size_t)mc * 128;
    const u16* Qb = q + row0 * 1024 + h * 64;
    int sr = tid >> 3, sc = (tid & 7) * 8;
#pragma unroll
    for (int p = 0; p < 4; p++) {
        int r = p * 32 + sr;
        *(uint4*)&Qs[r * 64 + sc] = *(const uint4*)&Qb[(size_t)r * 1024 + sc];
    }
    const float* Cb = ctx + (size_t)(b * 16 + h) * 4096;
#pragma unroll
    for (int rep = 0; rep < 16; ++rep) {
        int e = tid + rep * 256;
        int d = e >> 6, l = e & 63;
        Cs[l * 72 + d] = f2b(Cb[e]);   // store transposed: Cs[n=l][k=d]
    }
    __syncthreads();
    int quad = lane >> 4, mr = lane & 15;
    f32x4 acc[2][4] = {};
#pragma unroll
    for (int kk = 0; kk < 64; kk += 32) {
        bf16x8 a[2], bb[4];
#pragma unroll
        for (int i = 0; i < 2; i++) a[i] = *(const bf16x8*)&Qs[(w * 32 + i * 16 + mr) * 64 + kk + quad * 8];
#pragma unroll
        for (int j = 0; j < 4; j++) bb[j] = *(const bf16x8*)&Cs[(j * 16 + mr) * 72 + kk + quad * 8];
#pragma unroll
        for (int i = 0; i < 2; i++)
#pragma unroll
            for (int j = 0; j < 4; j++)
                acc[i][j] = __builtin_amdgcn_mfma_f32_16x16x32_bf16(a[i], bb[j], acc[i][j], 0, 0, 0);
    }
#pragma unroll
    for (int i = 0; i < 2; i++)
#pragma unroll
        for (int j = 0; j < 4; j++)
#pragma unroll
            for (int r = 0; r < 4; r++) {
                size_t row = row0 + w * 32 + i * 16 + quad * 4 + r;
                int col = h * 64 + j * 16 + mr;
                y[row * 1024 + col] = f2b(acc[i][j][r]);
            }
}

// ---------------- h_in = silu( LN(y)*sn_g+sn_b )*(1+scale)+shift ), bf16 in place ----------------
__global__ __launch_bounds__(256) void style_k(
    u16* __restrict__ y, const float* __restrict__ eo, const float* __restrict__ embb,
    const float* __restrict__ sng, const float* __restrict__ snb)
{
    int row = blockIdx.x, tid = threadIdx.x, b = row >> 12;
    u16* yr = y + (size_t)row * 1024;
    ushort4 u = *(const ushort4*)(yr + tid * 4);
    float vv[4] = { b2f(u.x), b2f(u.y), b2f(u.z), b2f(u.w) };
    float s = vv[0] + vv[1] + vv[2] + vv[3];
    float s2 = vv[0] * vv[0] + vv[1] * vv[1] + vv[2] * vv[2] + vv[3] * vv[3];
#pragma unroll
    for (int m = 32; m > 0; m >>= 1) { s += __shfl_xor(s, m, 64); s2 += __shfl_xor(s2, m, 64); }
    __shared__ float red[8];
    int w = tid >> 6, lane = tid & 63;
    if (lane == 0) { red[w] = s; red[4 + w] = s2; }
    __syncthreads();
    s = red[0] + red[1] + red[2] + red[3];
    s2 = red[4] + red[5] + red[6] + red[7];
    float mean = s * (1.f / 1024.f);
    float var = s2 * (1.f / 1024.f) - mean * mean;
    float rstd = rsqrtf(var + 1e-5f);
    int c = tid * 4;
    ushort4 o;
    u16* op = (u16*)&o;
#pragma unroll
    for (int i = 0; i < 4; i++) {
        int cc = c + i;
        float scale = eo[b * 2048 + cc] + embb[cc];
        float shift = eo[b * 2048 + 1024 + cc] + embb[1024 + cc];
        float hn = (vv[i] - mean) * rstd * sng[cc] + snb[cc];
        float hh = hn * (1.f + scale) + shift;
        op[i] = f2b(hh / (1.f + __expf(-hh)));
    }
    *(ushort4*)(yr + c) = o;
}

extern "C" void kernel_launch(void* const* d_in, const int* in_sizes, int n_in,
                              void* d_out, int out_size, void* d_ws, size_t ws_size,
                              hipStream_t stream)
{
    const float* x    = (const float*)d_in[0];
    const float* emb  = (const float*)d_in[1];
    const float* gate = (const float*)d_in[2];
    const float* ng   = (const float*)d_in[3];
    const float* nb   = (const float*)d_in[4];
    const float* Wq   = (const float*)d_in[5];
    const float* bq   = (const float*)d_in[6];
    const float* Wk   = (const float*)d_in[7];
    const float* bk   = (const float*)d_in[8];
    const float* Wv   = (const float*)d_in[9];
    const float* bv   = (const float*)d_in[10];
    const float* embW = (const float*)d_in[11];
    const float* embB = (const float*)d_in[12];
    const float* sng  = (const float*)d_in[13];
    const float* snb  = (const float*)d_in[14];
    const float* Wo   = (const float*)d_in[15];
    const float* ob   = (const float*)d_in[16];
    float* out = (float*)d_out;

    uint8_t* ws = (uint8_t*)d_ws;
    size_t off = 0;
    auto alloc = [&](size_t bytes) { void* p = ws + off; off += (bytes + 255) & ~(size_t)255; return p; };
    u16*   WqkvT   = (u16*)alloc(3072ull * 1024 * 2);    // 6 MB  (qT | kT | vT), bf16
    u16*   WoT     = (u16*)alloc(1024ull * 1024 * 2);    // 2 MB bf16
    float* biasAll = (float*)alloc(4096 * 4);
    u16*   XN      = (u16*)alloc(16384ull * 1024 * 2);   // 32 MB bf16: xn -> y -> h_in
    u16*   BUF0    = (u16*)alloc(16384ull * 1024 * 2);   // 32 MB bf16: K -> Q
    u16*   BUF1    = (u16*)alloc(16384ull * 1024 * 2);   // 32 MB bf16: V
    float* colsum  = (float*)alloc(4096 * 4);
    float* ctx     = (float*)alloc(64ull * 64 * 64 * 4); // 1 MB
    float* embout  = (float*)alloc(4ull * 2048 * 4);
    // peak ws use ~105.3 MB

    hipMemsetAsync(colsum, 0, 4096 * 4, stream);
    hipMemsetAsync(ctx, 0, 64ull * 64 * 64 * 4, stream);
    hipMemsetAsync(embout, 0, 4ull * 2048 * 4, stream);

    transpose_w<<<dim3(32, 32, 4), 256, 0, stream>>>(Wq, Wk, Wv, Wo, WqkvT, WoT);
    pack_bias<<<16, 256, 0, stream>>>(bq, bk, bv, ob, biasAll);
    ln_x<<<16384, 256, 0, stream>>>(x, ng, nb, XN);
    // K = xn @ Wk + bk ; V = xn @ Wv + bv
    gemm128<<<dim3(8, 128), 256, 0, stream>>>(XN, WqkvT + 1024 * 1024, biasAll + 1024, BUF0, nullptr, 1024, 0, nullptr, nullptr);
    gemm128<<<dim3(8, 128), 256, 0, stream>>>(XN, WqkvT + 2 * 1024 * 1024, biasAll + 2048, BUF1, nullptr, 1024, 0, nullptr, nullptr);
    // temporal softmax on K
    ksum<<<dim3(4, 16, 4), 256, 0, stream>>>(BUF0, colsum);
    knorm<<<dim3(4, 16, 4), 256, 0, stream>>>(BUF0, colsum);
    // ctx = Ksoft^T V
    ctx_k<<<dim3(8, 16, 4), 256, 0, stream>>>(BUF0, BUF1, ctx);
    // Q = xn @ Wq + bq (reuses BUF0; K is dead)
    gemm128<<<dim3(8, 128), 256, 0, stream>>>(XN, WqkvT, biasAll, BUF0, nullptr, 1024, 0, nullptr, nullptr);
    qsoftmax<<<65536, 256, 0, stream>>>(BUF0);
    embout_k<<<dim3(8, 8), 256, 0, stream>>>(emb, embW, embout);
    // y = Qsoft @ ctx (into XN; xn is dead)
    y_k<<<dim3(32, 16, 4), 256, 0, stream>>>(BUF0, ctx, XN);
    style_k<<<16384, 256, 0, stream>>>(XN, embout, embB, sng, snb);
    // out = x + gate * (h @ Wo + out_b), fp32 epilogue
    gemm128<<<dim3(8, 128), 256, 0, stream>>>(XN, WoT, biasAll + 3072, nullptr, out, 1024, 1, x, gate);
}

// Round 4
// 563.426 us; speedup vs baseline: 1.1493x; 1.1493x over previous
//
#include <hip/hip_runtime.h>
#include <stdint.h>

typedef unsigned short u16;
typedef float f32x4 __attribute__((ext_vector_type(4)));
typedef __bf16 bf16x8 __attribute__((ext_vector_type(8)));

__device__ __forceinline__ float b2f(u16 u) {
    union { unsigned int i; float f; } w; w.i = ((unsigned int)u) << 16; return w.f;
}
__device__ __forceinline__ u16 f2b(float f) {
    union { float f; unsigned int i; } w; w.f = f;
    unsigned int r = w.i + 0x7fffu + ((w.i >> 16) & 1u);
    return (u16)(r >> 16);
}
__device__ __forceinline__ void gload16(const void* g, void* l) {
    __builtin_amdgcn_global_load_lds(
        (const __attribute__((address_space(1))) unsigned int*)g,
        (__attribute__((address_space(3))) unsigned int*)l, 16, 0, 0);
}

// ---------------- transpose+cast weights: W[k][n] fp32 (1024x1024) -> Wt[n][k] bf16 ----------------
__global__ __launch_bounds__(256) void transpose_w(
    const float* __restrict__ Wq, const float* __restrict__ Wk, const float* __restrict__ Wv,
    const float* __restrict__ Wo, u16* __restrict__ WqkvT, u16* __restrict__ WoT)
{
    const float* src = (blockIdx.z == 0) ? Wq : (blockIdx.z == 1) ? Wk : (blockIdx.z == 2) ? Wv : Wo;
    u16* dst = (blockIdx.z < 3) ? (WqkvT + (size_t)blockIdx.z * 1024 * 1024) : WoT;
    __shared__ u16 tile[32][33];
    int tx = threadIdx.x & 31, ty = threadIdx.x >> 5;  // 32 x 8
    int n0 = blockIdx.x * 32, k0 = blockIdx.y * 32;
#pragma unroll
    for (int i = 0; i < 4; i++) tile[ty + 8 * i][tx] = f2b(src[(size_t)(k0 + ty + 8 * i) * 1024 + n0 + tx]);
    __syncthreads();
#pragma unroll
    for (int i = 0; i < 4; i++) dst[(size_t)(n0 + ty + 8 * i) * 1024 + k0 + tx] = tile[tx][ty + 8 * i];
}

// ---------------- pack biases fp32: [bq|bk|bv|out_b] = 4096 ----------------
__global__ __launch_bounds__(256) void pack_bias(
    const float* __restrict__ bq, const float* __restrict__ bk, const float* __restrict__ bv,
    const float* __restrict__ ob, float* __restrict__ biasAll)
{
    int i = blockIdx.x * 256 + threadIdx.x;
    float v;
    if (i < 1024) v = bq[i];
    else if (i < 2048) v = bk[i - 1024];
    else if (i < 3072) v = bv[i - 2048];
    else v = ob[i - 3072];
    biasAll[i] = v;
}

// ---------------- LayerNorm(x fp32) -> xn (bf16), one row per block ----------------
__global__ __launch_bounds__(256) void ln_x(
    const float* __restrict__ x, const float* __restrict__ g, const float* __restrict__ bt,
    u16* __restrict__ xn)
{
    int row = blockIdx.x, tid = threadIdx.x;
    const float* xr = x + (size_t)row * 1024;
    float4 u = *(const float4*)(xr + tid * 4);
    float v0 = u.x, v1 = u.y, v2 = u.z, v3 = u.w;
    float s = v0 + v1 + v2 + v3;
    float s2 = v0 * v0 + v1 * v1 + v2 * v2 + v3 * v3;
#pragma unroll
    for (int m = 32; m > 0; m >>= 1) { s += __shfl_xor(s, m, 64); s2 += __shfl_xor(s2, m, 64); }
    __shared__ float red[8];
    int w = tid >> 6, lane = tid & 63;
    if (lane == 0) { red[w] = s; red[4 + w] = s2; }
    __syncthreads();
    s = red[0] + red[1] + red[2] + red[3];
    s2 = red[4] + red[5] + red[6] + red[7];
    float mean = s * (1.f / 1024.f);
    float var = s2 * (1.f / 1024.f) - mean * mean;
    float rstd = rsqrtf(var + 1e-5f);
    int c = tid * 4;
    float4 gg = *(const float4*)(g + c);
    float4 bb = *(const float4*)(bt + c);
    ushort4 o;
    o.x = f2b((v0 - mean) * rstd * gg.x + bb.x);
    o.y = f2b((v1 - mean) * rstd * gg.y + bb.y);
    o.z = f2b((v2 - mean) * rstd * gg.z + bb.z);
    o.w = f2b((v3 - mean) * rstd * gg.w + bb.w);
    *(ushort4*)(xn + (size_t)row * 1024 + c) = o;
}

// ---------------- 128x128 MFMA GEMM, K=1024, gload16 staging, XCD swizzle ----------------
// mode 0: KV fused (gridDim.x=16): col<1024 -> Kb, else Vb (bf16, stride 1024)
// mode 1: Q + fused feature-softmax over dh=64 -> Cb (bf16)
// mode 2: out = Xf + gate*(A@B+bias) -> Cf (fp32)
__global__ __launch_bounds__(256) void gemm128(
    const u16* __restrict__ A, const u16* __restrict__ Bt, const float* __restrict__ bias,
    int mode, u16* __restrict__ Kb, u16* __restrict__ Vb, u16* __restrict__ Cb,
    float* __restrict__ Cf, const float* __restrict__ Xf, const float* __restrict__ gate)
{
    const int K = 1024;
    __shared__ __align__(16) u16 As[128 * 64];
    __shared__ __align__(16) u16 Bs[128 * 64];
    int tid = threadIdx.x, lane = tid & 63, w = tid >> 6;
    int wm = w >> 1, wn = w & 1;
    // XCD-aware swizzle: gridDim.y==128 rows; each XCD owns 16 consecutive row-tiles
    // and walks cols outer (rows fast) so its 4MB A-set stays L2-resident.
    int NB = gridDim.x;
    int lid = blockIdx.y * NB + blockIdx.x;
    int xcd = lid & 7;
    int i_ = lid >> 3;
    int rowLocal = i_ & 15;       // fast
    int colIdx = i_ >> 4;
    size_t rowbase = (size_t)(xcd * 16 + rowLocal) * 128;
    size_t colbase = (size_t)colIdx * 128;
    const u16* Ab = A + rowbase * K;
    const u16* Bb = Bt + colbase * K;
    f32x4 acc[4][4] = {};
    int quad = lane >> 4, mr = lane & 15;
    for (int k0 = 0; k0 < K; k0 += 64) {
#pragma unroll
        for (int j = 0; j < 4; j++) {
            int r = w * 32 + j * 8 + (lane >> 3), c = (lane & 7) * 8;
            gload16(Ab + (size_t)r * K + k0 + c, &As[(w * 32 + j * 8) * 64]);
            gload16(Bb + (size_t)r * K + k0 + c, &Bs[(w * 32 + j * 8) * 64]);
        }
        __syncthreads();
#pragma unroll
        for (int kk = 0; kk < 64; kk += 32) {
            bf16x8 a[4], bf[4];
#pragma unroll
            for (int i = 0; i < 4; i++) a[i] = *(const bf16x8*)&As[(wm * 64 + i * 16 + mr) * 64 + kk + quad * 8];
#pragma unroll
            for (int j = 0; j < 4; j++) bf[j] = *(const bf16x8*)&Bs[(wn * 64 + j * 16 + mr) * 64 + kk + quad * 8];
#pragma unroll
            for (int i = 0; i < 4; i++)
#pragma unroll
                for (int j = 0; j < 4; j++)
                    acc[i][j] = __builtin_amdgcn_mfma_f32_16x16x32_bf16(a[i], bf[j], acc[i][j], 0, 0, 0);
        }
        __syncthreads();
    }
    int colj[4]; float bj[4];
#pragma unroll
    for (int j = 0; j < 4; j++) { colj[j] = (int)colbase + wn * 64 + j * 16 + mr; bj[j] = bias[colj[j]]; }
    if (mode == 1) {
        // fused softmax over head dim (64 cols = 4 j-regs x 16 mr-lanes), per output row
#pragma unroll
        for (int i = 0; i < 4; i++) {
#pragma unroll
            for (int r = 0; r < 4; r++) {
                size_t row = rowbase + wm * 64 + i * 16 + quad * 4 + r;
                float v[4], m = -1e30f, ss = 0.f;
#pragma unroll
                for (int j = 0; j < 4; j++) { v[j] = acc[i][j][r] + bj[j]; m = fmaxf(m, v[j]); }
#pragma unroll
                for (int s = 1; s < 16; s <<= 1) m = fmaxf(m, __shfl_xor(m, s, 64));
#pragma unroll
                for (int j = 0; j < 4; j++) { v[j] = __expf(v[j] - m); ss += v[j]; }
#pragma unroll
                for (int s = 1; s < 16; s <<= 1) ss += __shfl_xor(ss, s, 64);
                float inv = 1.f / ss;
#pragma unroll
                for (int j = 0; j < 4; j++) Cb[row * 1024 + colj[j]] = f2b(v[j] * inv);
            }
        }
        return;
    }
#pragma unroll
    for (int j = 0; j < 4; j++) {
        int col = colj[j];
#pragma unroll
        for (int i = 0; i < 4; i++) {
#pragma unroll
            for (int r = 0; r < 4; r++) {
                size_t row = rowbase + wm * 64 + i * 16 + quad * 4 + r;
                float v = acc[i][j][r] + bj[j];
                if (mode == 0) {
                    u16* dst = (col < 1024) ? Kb : Vb;
                    dst[row * 1024 + (col & 1023)] = f2b(v);
                } else {
                    int b_ = (int)(row >> 12);
                    Cf[row * 1024 + col] = Xf[row * 1024 + col] + gate[b_ * 1024 + col] * v;
                }
            }
        }
    }
}

// ---------------- temporal k softmax pass 1: column sums of exp (stride 1024) ----------------
__global__ __launch_bounds__(256) void ksum(const u16* __restrict__ k, float* __restrict__ colsum)
{
    int c = blockIdx.x * 256 + threadIdx.x;
    int b = blockIdx.z, ch = blockIdx.y;  // 16 chunks x 256 rows
    const u16* p = k + ((size_t)b * 4096 + ch * 256) * 1024 + c;
    float s = 0.f;
#pragma unroll 4
    for (int t = 0; t < 256; t++) s += __expf(b2f(p[(size_t)t * 1024]));
    atomicAdd(&colsum[b * 1024 + c], s);
}

// ---------------- ctx[b,h] = softmax_t(K)^T V, normalize fused (exp*inv_colsum) ----------------
__global__ __launch_bounds__(256) void ctx_k(
    const u16* __restrict__ kbuf, const u16* __restrict__ vbuf,
    const float* __restrict__ colsum, float* __restrict__ ctx)
{
    int ch = blockIdx.x, h = blockIdx.y, b = blockIdx.z;
    __shared__ __align__(16) float Es[16][64];
    __shared__ __align__(16) float Vs[16][64];
    int tid = threadIdx.x;
    int td = tid >> 4, tl = tid & 15;
    float invc = 1.f / colsum[b * 1024 + h * 64 + (tid & 63)];
    float acc[4][4] = {};
    size_t rowbase = (size_t)b * 4096 + ch * 512;
    for (int g = 0; g < 32; ++g) {
#pragma unroll
        for (int rep = 0; rep < 4; ++rep) {
            int e = tid + rep * 256;
            int r = e >> 6, cc = e & 63;
            size_t base = (rowbase + g * 16 + r) * 1024 + h * 64 + cc;
            Es[r][cc] = __expf(b2f(kbuf[base])) * invc;
            Vs[r][cc] = b2f(vbuf[base]);
        }
        __syncthreads();
#pragma unroll
        for (int n = 0; n < 16; n++) {
            f32x4 e4 = *(const f32x4*)&Es[n][td * 4];
            f32x4 v4 = *(const f32x4*)&Vs[n][tl * 4];
#pragma unroll
            for (int i = 0; i < 4; i++)
#pragma unroll
                for (int j = 0; j < 4; j++) acc[i][j] += e4[i] * v4[j];
        }
        __syncthreads();
    }
    float* cb = ctx + (size_t)(b * 16 + h) * 4096;
#pragma unroll
    for (int i = 0; i < 4; i++)
#pragma unroll
        for (int j = 0; j < 4; j++)
            atomicAdd(&cb[(td * 4 + i) * 64 + tl * 4 + j], acc[i][j]);
}

// ---------------- emb_out = silu(emb) @ emb_W (fp32, atomic over k chunks) ----------------
__global__ __launch_bounds__(256) void embout_k(
    const float* __restrict__ emb, const float* __restrict__ embW, float* __restrict__ eo)
{
    int cb = blockIdx.x, kc = blockIdx.y;
    __shared__ float semb[512];
    int tid = threadIdx.x;
#pragma unroll
    for (int i = 0; i < 2; i++) {
        int e = tid + i * 256;
        int b = e >> 7, kk = e & 127;
        float xv = emb[b * 1024 + kc * 128 + kk];
        semb[e] = xv / (1.f + __expf(-xv));
    }
    __syncthreads();
    int o = cb * 256 + tid;
    float a0 = 0, a1 = 0, a2 = 0, a3 = 0;
    for (int kk = 0; kk < 128; kk++) {
        float wv = embW[(size_t)(kc * 128 + kk) * 2048 + o];
        a0 += semb[kk] * wv; a1 += semb[128 + kk] * wv;
        a2 += semb[256 + kk] * wv; a3 += semb[384 + kk] * wv;
    }
    atomicAdd(&eo[o], a0);
    atomicAdd(&eo[2048 + o], a1);
    atomicAdd(&eo[4096 + o], a2);
    atomicAdd(&eo[6144 + o], a3);
}

// ---------------- y = q_soft @ ctx per head (MFMA, K=64) ----------------
__global__ __launch_bounds__(256) void y_k(
    const u16* __restrict__ q, const float* __restrict__ ctx, u16* __restrict__ y)
{
    int mc = blockIdx.x, h = blockIdx.y, b = blockIdx.z;
    __shared__ __align__(16) u16 Qs[128 * 64];
    __shared__ __align__(16) u16 Cs[64 * 72];
    int tid = threadIdx.x, lane = tid & 63, w = tid >> 6;
    size_t row0 = (size_t)b * 4096 + (size_t)mc * 128;
    const u16* Qb = q + row0 * 1024 + h * 64;
    int sr = tid >> 3, sc = (tid & 7) * 8;
#pragma unroll
    for (int p = 0; p < 4; p++) {
        int r = p * 32 + sr;
        *(uint4*)&Qs[r * 64 + sc] = *(const uint4*)&Qb[(size_t)r * 1024 + sc];
    }
    const float* Cb = ctx + (size_t)(b * 16 + h) * 4096;
#pragma unroll
    for (int rep = 0; rep < 16; ++rep) {
        int e = tid + rep * 256;
        int d = e >> 6, l = e & 63;
        Cs[l * 72 + d] = f2b(Cb[e]);   // transposed: Cs[n=l][k=d]
    }
    __syncthreads();
    int quad = lane >> 4, mr = lane & 15;
    f32x4 acc[2][4] = {};
#pragma unroll
    for (int kk = 0; kk < 64; kk += 32) {
        bf16x8 a[2], bb[4];
#pragma unroll
        for (int i = 0; i < 2; i++) a[i] = *(const bf16x8*)&Qs[(w * 32 + i * 16 + mr) * 64 + kk + quad * 8];
#pragma unroll
        for (int j = 0; j < 4; j++) bb[j] = *(const bf16x8*)&Cs[(j * 16 + mr) * 72 + kk + quad * 8];
#pragma unroll
        for (int i = 0; i < 2; i++)
#pragma unroll
            for (int j = 0; j < 4; j++)
                acc[i][j] = __builtin_amdgcn_mfma_f32_16x16x32_bf16(a[i], bb[j], acc[i][j], 0, 0, 0);
    }
#pragma unroll
    for (int i = 0; i < 2; i++)
#pragma unroll
        for (int j = 0; j < 4; j++)
#pragma unroll
            for (int r = 0; r < 4; r++) {
                size_t row = row0 + w * 32 + i * 16 + quad * 4 + r;
                int col = h * 64 + j * 16 + mr;
                y[row * 1024 + col] = f2b(acc[i][j][r]);
            }
}

// ---------------- h_in = silu( LN(y)*sn_g+sn_b )*(1+scale)+shift ), bf16 in place ----------------
__global__ __launch_bounds__(256) void style_k(
    u16* __restrict__ y, const float* __restrict__ eo, const float* __restrict__ embb,
    const float* __restrict__ sng, const float* __restrict__ snb)
{
    int row = blockIdx.x, tid = threadIdx.x, b = row >> 12;
    u16* yr = y + (size_t)row * 1024;
    ushort4 u = *(const ushort4*)(yr + tid * 4);
    float vv[4] = { b2f(u.x), b2f(u.y), b2f(u.z), b2f(u.w) };
    float s = vv[0] + vv[1] + vv[2] + vv[3];
    float s2 = vv[0] * vv[0] + vv[1] * vv[1] + vv[2] * vv[2] + vv[3] * vv[3];
#pragma unroll
    for (int m = 32; m > 0; m >>= 1) { s += __shfl_xor(s, m, 64); s2 += __shfl_xor(s2, m, 64); }
    __shared__ float red[8];
    int w = tid >> 6, lane = tid & 63;
    if (lane == 0) { red[w] = s; red[4 + w] = s2; }
    __syncthreads();
    s = red[0] + red[1] + red[2] + red[3];
    s2 = red[4] + red[5] + red[6] + red[7];
    float mean = s * (1.f / 1024.f);
    float var = s2 * (1.f / 1024.f) - mean * mean;
    float rstd = rsqrtf(var + 1e-5f);
    int c = tid * 4;
    ushort4 o;
    u16* op = (u16*)&o;
#pragma unroll
    for (int i = 0; i < 4; i++) {
        int cc = c + i;
        float scale = eo[b * 2048 + cc] + embb[cc];
        float shift = eo[b * 2048 + 1024 + cc] + embb[1024 + cc];
        float hn = (vv[i] - mean) * rstd * sng[cc] + snb[cc];
        float hh = hn * (1.f + scale) + shift;
        op[i] = f2b(hh / (1.f + __expf(-hh)));
    }
    *(ushort4*)(yr + c) = o;
}

extern "C" void kernel_launch(void* const* d_in, const int* in_sizes, int n_in,
                              void* d_out, int out_size, void* d_ws, size_t ws_size,
                              hipStream_t stream)
{
    const float* x    = (const float*)d_in[0];
    const float* emb  = (const float*)d_in[1];
    const float* gate = (const float*)d_in[2];
    const float* ng   = (const float*)d_in[3];
    const float* nb   = (const float*)d_in[4];
    const float* Wq   = (const float*)d_in[5];
    const float* bq   = (const float*)d_in[6];
    const float* Wk   = (const float*)d_in[7];
    const float* bk   = (const float*)d_in[8];
    const float* Wv   = (const float*)d_in[9];
    const float* bv   = (const float*)d_in[10];
    const float* embW = (const float*)d_in[11];
    const float* embB = (const float*)d_in[12];
    const float* sng  = (const float*)d_in[13];
    const float* snb  = (const float*)d_in[14];
    const float* Wo   = (const float*)d_in[15];
    const float* ob   = (const float*)d_in[16];
    float* out = (float*)d_out;

    uint8_t* ws = (uint8_t*)d_ws;
    size_t off = 0;
    auto alloc = [&](size_t bytes) { void* p = ws + off; off += (bytes + 255) & ~(size_t)255; return p; };
    u16*   WqkvT   = (u16*)alloc(3072ull * 1024 * 2);    // 6 MB (qT | kT | vT) bf16
    u16*   WoT     = (u16*)alloc(1024ull * 1024 * 2);    // 2 MB bf16
    float* biasAll = (float*)alloc(4096 * 4);
    u16*   XN      = (u16*)alloc(16384ull * 1024 * 2);   // 32 MB: xn -> y -> h_in
    u16*   BUF0    = (u16*)alloc(16384ull * 1024 * 2);   // 32 MB: K -> Qsoft
    u16*   BUF1    = (u16*)alloc(16384ull * 1024 * 2);   // 32 MB: V
    float* colsum  = (float*)alloc(4096 * 4);
    float* ctx     = (float*)alloc(64ull * 64 * 64 * 4); // 1 MB
    float* embout  = (float*)alloc(4ull * 2048 * 4);
    // peak ws ~105.3 MB

    hipMemsetAsync(colsum, 0, 4096 * 4, stream);
    hipMemsetAsync(ctx, 0, 64ull * 64 * 64 * 4, stream);
    hipMemsetAsync(embout, 0, 4ull * 2048 * 4, stream);

    transpose_w<<<dim3(32, 32, 4), 256, 0, stream>>>(Wq, Wk, Wv, Wo, WqkvT, WoT);
    pack_bias<<<16, 256, 0, stream>>>(bq, bk, bv, ob, biasAll);
    ln_x<<<16384, 256, 0, stream>>>(x, ng, nb, XN);
    // K|V = xn @ [Wk|Wv] + [bk|bv]  (fused, N=2048)
    gemm128<<<dim3(16, 128), 256, 0, stream>>>(XN, WqkvT + 1024 * 1024, biasAll + 1024, 0,
                                               BUF0, BUF1, nullptr, nullptr, nullptr, nullptr);
    ksum<<<dim3(4, 16, 4), 256, 0, stream>>>(BUF0, colsum);
    ctx_k<<<dim3(8, 16, 4), 256, 0, stream>>>(BUF0, BUF1, colsum, ctx);
    // Qsoft = softmax_dh(xn @ Wq + bq)  (fused epilogue; overwrites BUF0, K dead)
    gemm128<<<dim3(8, 128), 256, 0, stream>>>(XN, WqkvT, biasAll, 1,
                                              nullptr, nullptr, BUF0, nullptr, nullptr, nullptr);
    embout_k<<<dim3(8, 8), 256, 0, stream>>>(emb, embW, embout);
    y_k<<<dim3(32, 16, 4), 256, 0, stream>>>(BUF0, ctx, XN);
    style_k<<<16384, 256, 0, stream>>>(XN, embout, embB, sng, snb);
    // out = x + gate * (h @ Wo + out_b), fp32 epilogue
    gemm128<<<dim3(8, 128), 256, 0, stream>>>(XN, WoT, biasAll + 3072, 2,
                                              nullptr, nullptr, nullptr, out, x, gate);
}

// Round 5
// 502.429 us; speedup vs baseline: 1.2888x; 1.1214x over previous
//
#include <hip/hip_runtime.h>
#include <stdint.h>

typedef unsigned short u16;
typedef float f32x4 __attribute__((ext_vector_type(4)));
typedef __bf16 bf16x8 __attribute__((ext_vector_type(8)));

__device__ __forceinline__ float b2f(u16 u) {
    union { unsigned int i; float f; } w; w.i = ((unsigned int)u) << 16; return w.f;
}
__device__ __forceinline__ u16 f2b(float f) {
    union { float f; unsigned int i; } w; w.f = f;
    unsigned int r = w.i + 0x7fffu + ((w.i >> 16) & 1u);
    return (u16)(r >> 16);
}
__device__ __forceinline__ void gload16(const void* g, void* l) {
    __builtin_amdgcn_global_load_lds(
        (const __attribute__((address_space(1))) unsigned int*)g,
        (__attribute__((address_space(3))) unsigned int*)l, 16, 0, 0);
}

// ---------------- prep: transpose+cast 4 weights, pack biases, zero scratch ----------------
// blocks [0,4096): transpose 32x32 tiles; [4096,4112): bias; [4112,4380): zero 1097728 B
__global__ __launch_bounds__(256) void prep_k(
    const float* __restrict__ Wq, const float* __restrict__ Wk, const float* __restrict__ Wv,
    const float* __restrict__ Wo, const float* __restrict__ bq, const float* __restrict__ bk,
    const float* __restrict__ bv, const float* __restrict__ ob,
    u16* __restrict__ WqkvT, u16* __restrict__ WoT, float* __restrict__ biasAll,
    float* __restrict__ zeroBase)
{
    int bz = blockIdx.x, tid = threadIdx.x;
    if (bz < 4096) {
        int z = bz >> 10, rem = bz & 1023;
        const float* src = (z == 0) ? Wq : (z == 1) ? Wk : (z == 2) ? Wv : Wo;
        u16* dst = (z < 3) ? (WqkvT + (size_t)z * 1024 * 1024) : WoT;
        __shared__ u16 tile[32][33];
        int tx = tid & 31, ty = tid >> 5;  // 32 x 8
        int n0 = (rem & 31) * 32, k0 = (rem >> 5) * 32;
#pragma unroll
        for (int i = 0; i < 4; i++) tile[ty + 8 * i][tx] = f2b(src[(size_t)(k0 + ty + 8 * i) * 1024 + n0 + tx]);
        __syncthreads();
#pragma unroll
        for (int i = 0; i < 4; i++) dst[(size_t)(n0 + ty + 8 * i) * 1024 + k0 + tx] = tile[tx][ty + 8 * i];
    } else if (bz < 4112) {
        int i = (bz - 4096) * 256 + tid;
        float v;
        if (i < 1024) v = bq[i];
        else if (i < 2048) v = bk[i - 1024];
        else if (i < 3072) v = bv[i - 2048];
        else v = ob[i - 3072];
        biasAll[i] = v;
    } else {
        int e = (bz - 4112) * 256 + tid;           // float4 index
        ((float4*)zeroBase)[e] = make_float4(0.f, 0.f, 0.f, 0.f);
    }
}

// ---------------- LayerNorm(x fp32) -> xn (bf16), one row per block ----------------
__global__ __launch_bounds__(256) void ln_x(
    const float* __restrict__ x, const float* __restrict__ g, const float* __restrict__ bt,
    u16* __restrict__ xn)
{
    int row = blockIdx.x, tid = threadIdx.x;
    const float* xr = x + (size_t)row * 1024;
    float4 u = *(const float4*)(xr + tid * 4);
    float v0 = u.x, v1 = u.y, v2 = u.z, v3 = u.w;
    float s = v0 + v1 + v2 + v3;
    float s2 = v0 * v0 + v1 * v1 + v2 * v2 + v3 * v3;
#pragma unroll
    for (int m = 32; m > 0; m >>= 1) { s += __shfl_xor(s, m, 64); s2 += __shfl_xor(s2, m, 64); }
    __shared__ float red[8];
    int w = tid >> 6, lane = tid & 63;
    if (lane == 0) { red[w] = s; red[4 + w] = s2; }
    __syncthreads();
    s = red[0] + red[1] + red[2] + red[3];
    s2 = red[4] + red[5] + red[6] + red[7];
    float mean = s * (1.f / 1024.f);
    float var = s2 * (1.f / 1024.f) - mean * mean;
    float rstd = rsqrtf(var + 1e-5f);
    int c = tid * 4;
    float4 gg = *(const float4*)(g + c);
    float4 bb = *(const float4*)(bt + c);
    ushort4 o;
    o.x = f2b((v0 - mean) * rstd * gg.x + bb.x);
    o.y = f2b((v1 - mean) * rstd * gg.y + bb.y);
    o.z = f2b((v2 - mean) * rstd * gg.z + bb.z);
    o.w = f2b((v3 - mean) * rstd * gg.w + bb.w);
    *(ushort4*)(xn + (size_t)row * 1024 + c) = o;
}

// ---------------- 128x128 MFMA GEMM, K=1024, gload16 staging, XCD swizzle ----------------
// mode 0: fused QKV (grid 24x128): col<1024 Q+softmax -> Qb; <2048 K -> exp stored + colsum atomics; else V -> Vb
// mode 2: out = Xf + gate*(A@B+bias) -> Cf (fp32)
__global__ __launch_bounds__(256) void gemm128(
    const u16* __restrict__ A, const u16* __restrict__ Bt, const float* __restrict__ bias,
    int mode, u16* __restrict__ Qb, u16* __restrict__ Kb, u16* __restrict__ Vb,
    float* __restrict__ colsum, float* __restrict__ Cf,
    const float* __restrict__ Xf, const float* __restrict__ gate)
{
    const int K = 1024;
    __shared__ __align__(16) u16 As[128 * 64];
    __shared__ __align__(16) u16 Bs[128 * 64];
    int tid = threadIdx.x, lane = tid & 63, w = tid >> 6;
    int wm = w >> 1, wn = w & 1;
    // XCD swizzle: each XCD owns 16 row-tiles (4MB A), walks cols outer.
    int NB = gridDim.x;
    int lid = blockIdx.y * NB + blockIdx.x;
    int xcd = lid & 7;
    int i_ = lid >> 3;
    int rowLocal = i_ & 15;
    int colIdx = i_ >> 4;
    size_t rowbase = (size_t)(xcd * 16 + rowLocal) * 128;
    size_t colbase = (size_t)colIdx * 128;
    const u16* Ab = A + rowbase * K;
    const u16* Bb = Bt + colbase * K;
    f32x4 acc[4][4] = {};
    int quad = lane >> 4, mr = lane & 15;
    for (int k0 = 0; k0 < K; k0 += 64) {
#pragma unroll
        for (int j = 0; j < 4; j++) {
            int r = w * 32 + j * 8 + (lane >> 3), c = (lane & 7) * 8;
            gload16(Ab + (size_t)r * K + k0 + c, &As[(w * 32 + j * 8) * 64]);
            gload16(Bb + (size_t)r * K + k0 + c, &Bs[(w * 32 + j * 8) * 64]);
        }
        __syncthreads();
#pragma unroll
        for (int kk = 0; kk < 64; kk += 32) {
            bf16x8 a[4], bf[4];
#pragma unroll
            for (int i = 0; i < 4; i++) a[i] = *(const bf16x8*)&As[(wm * 64 + i * 16 + mr) * 64 + kk + quad * 8];
#pragma unroll
            for (int j = 0; j < 4; j++) bf[j] = *(const bf16x8*)&Bs[(wn * 64 + j * 16 + mr) * 64 + kk + quad * 8];
#pragma unroll
            for (int i = 0; i < 4; i++)
#pragma unroll
                for (int j = 0; j < 4; j++)
                    acc[i][j] = __builtin_amdgcn_mfma_f32_16x16x32_bf16(a[i], bf[j], acc[i][j], 0, 0, 0);
        }
        __syncthreads();
    }
    int colj[4]; float bj[4];
#pragma unroll
    for (int j = 0; j < 4; j++) { colj[j] = (int)colbase + wn * 64 + j * 16 + mr; bj[j] = bias[colj[j]]; }
    int creg = (int)colbase + wn * 64;   // wave-uniform region start
    if (mode == 0) {
        if (creg < 1024) {
            // Q + feature softmax over this wave's 64-col head span
#pragma unroll
            for (int i = 0; i < 4; i++) {
#pragma unroll
                for (int r = 0; r < 4; r++) {
                    size_t row = rowbase + wm * 64 + i * 16 + quad * 4 + r;
                    float v[4], m = -1e30f, ss = 0.f;
#pragma unroll
                    for (int j = 0; j < 4; j++) { v[j] = acc[i][j][r] + bj[j]; m = fmaxf(m, v[j]); }
#pragma unroll
                    for (int s = 1; s < 16; s <<= 1) m = fmaxf(m, __shfl_xor(m, s, 64));
#pragma unroll
                    for (int j = 0; j < 4; j++) { v[j] = __expf(v[j] - m); ss += v[j]; }
#pragma unroll
                    for (int s = 1; s < 16; s <<= 1) ss += __shfl_xor(ss, s, 64);
                    float inv = 1.f / ss;
#pragma unroll
                    for (int j = 0; j < 4; j++) Qb[row * 1024 + colj[j]] = f2b(v[j] * inv);
                }
            }
        } else if (creg < 2048) {
            // K: store exp(k) bf16; accumulate per-column exp-sums -> colsum
            int b_ = (int)(rowbase >> 12);
            float csum[4] = {};
#pragma unroll
            for (int j = 0; j < 4; j++) {
#pragma unroll
                for (int i = 0; i < 4; i++) {
#pragma unroll
                    for (int r = 0; r < 4; r++) {
                        size_t row = rowbase + wm * 64 + i * 16 + quad * 4 + r;
                        float e = __expf(acc[i][j][r] + bj[j]);
                        Kb[row * 1024 + (colj[j] - 1024)] = f2b(e);
                        csum[j] += e;
                    }
                }
            }
#pragma unroll
            for (int j = 0; j < 4; j++) {
                csum[j] += __shfl_xor(csum[j], 16, 64);
                csum[j] += __shfl_xor(csum[j], 32, 64);
                if (quad == 0) atomicAdd(&colsum[b_ * 1024 + (colj[j] - 1024)], csum[j]);
            }
        } else {
            // V: plain store
#pragma unroll
            for (int j = 0; j < 4; j++) {
#pragma unroll
                for (int i = 0; i < 4; i++) {
#pragma unroll
                    for (int r = 0; r < 4; r++) {
                        size_t row = rowbase + wm * 64 + i * 16 + quad * 4 + r;
                        Vb[row * 1024 + (colj[j] - 2048)] = f2b(acc[i][j][r] + bj[j]);
                    }
                }
            }
        }
        return;
    }
    // mode 2: out = Xf + gate * (A@B + bias)
    int b_ = (int)(rowbase >> 12);
#pragma unroll
    for (int j = 0; j < 4; j++) {
        float gv = gate[b_ * 1024 + colj[j]];
#pragma unroll
        for (int i = 0; i < 4; i++) {
#pragma unroll
            for (int r = 0; r < 4; r++) {
                size_t row = rowbase + wm * 64 + i * 16 + quad * 4 + r;
                float v = acc[i][j][r] + bj[j];
                Cf[row * 1024 + colj[j]] = Xf[row * 1024 + colj[j]] + gv * v;
            }
        }
    }
}

// ---------------- ctx[b,h] = (expK * inv_colsum)^T V ----------------
__global__ __launch_bounds__(256) void ctx_k(
    const u16* __restrict__ kbuf, const u16* __restrict__ vbuf,
    const float* __restrict__ colsum, float* __restrict__ ctx)
{
    int ch = blockIdx.x, h = blockIdx.y, b = blockIdx.z;
    __shared__ __align__(16) float Es[16][64];
    __shared__ __align__(16) float Vs[16][64];
    int tid = threadIdx.x;
    int td = tid >> 4, tl = tid & 15;
    float invc = 1.f / colsum[b * 1024 + h * 64 + (tid & 63)];
    float acc[4][4] = {};
    size_t rowbase = (size_t)b * 4096 + ch * 512;
    for (int g = 0; g < 32; ++g) {
#pragma unroll
        for (int rep = 0; rep < 4; ++rep) {
            int e = tid + rep * 256;
            int r = e >> 6, cc = e & 63;
            size_t base = (rowbase + g * 16 + r) * 1024 + h * 64 + cc;
            Es[r][cc] = b2f(kbuf[base]) * invc;   // kbuf holds exp(k) already
            Vs[r][cc] = b2f(vbuf[base]);
        }
        __syncthreads();
#pragma unroll
        for (int n = 0; n < 16; n++) {
            f32x4 e4 = *(const f32x4*)&Es[n][td * 4];
            f32x4 v4 = *(const f32x4*)&Vs[n][tl * 4];
#pragma unroll
            for (int i = 0; i < 4; i++)
#pragma unroll
                for (int j = 0; j < 4; j++) acc[i][j] += e4[i] * v4[j];
        }
        __syncthreads();
    }
    float* cb = ctx + (size_t)(b * 16 + h) * 4096;
#pragma unroll
    for (int i = 0; i < 4; i++)
#pragma unroll
        for (int j = 0; j < 4; j++)
            atomicAdd(&cb[(td * 4 + i) * 64 + tl * 4 + j], acc[i][j]);
}

// ---------------- emb_out = silu(emb) @ emb_W (fp32, atomic over k chunks) ----------------
__global__ __launch_bounds__(256) void embout_k(
    const float* __restrict__ emb, const float* __restrict__ embW, float* __restrict__ eo)
{
    int cb = blockIdx.x, kc = blockIdx.y;
    __shared__ float semb[512];
    int tid = threadIdx.x;
#pragma unroll
    for (int i = 0; i < 2; i++) {
        int e = tid + i * 256;
        int b = e >> 7, kk = e & 127;
        float xv = emb[b * 1024 + kc * 128 + kk];
        semb[e] = xv / (1.f + __expf(-xv));
    }
    __syncthreads();
    int o = cb * 256 + tid;
    float a0 = 0, a1 = 0, a2 = 0, a3 = 0;
    for (int kk = 0; kk < 128; kk++) {
        float wv = embW[(size_t)(kc * 128 + kk) * 2048 + o];
        a0 += semb[kk] * wv; a1 += semb[128 + kk] * wv;
        a2 += semb[256 + kk] * wv; a3 += semb[384 + kk] * wv;
    }
    atomicAdd(&eo[o], a0);
    atomicAdd(&eo[2048 + o], a1);
    atomicAdd(&eo[4096 + o], a2);
    atomicAdd(&eo[6144 + o], a3);
}

// ---------------- y = q_soft @ ctx per head (MFMA, K=64) ----------------
__global__ __launch_bounds__(256) void y_k(
    const u16* __restrict__ q, const float* __restrict__ ctx, u16* __restrict__ y)
{
    int mc = blockIdx.x, h = blockIdx.y, b = blockIdx.z;
    __shared__ __align__(16) u16 Qs[128 * 64];
    __shared__ __align__(16) u16 Cs[64 * 72];
    int tid = threadIdx.x, lane = tid & 63, w = tid >> 6;
    size_t row0 = (size_t)b * 4096 + (size_t)mc * 128;
    const u16* Qb = q + row0 * 1024 + h * 64;
    int sr = tid >> 3, sc = (tid & 7) * 8;
#pragma unroll
    for (int p = 0; p < 4; p++) {
        int r = p * 32 + sr;
        *(uint4*)&Qs[r * 64 + sc] = *(const uint4*)&Qb[(size_t)r * 1024 + sc];
    }
    const float* Cb = ctx + (size_t)(b * 16 + h) * 4096;
#pragma unroll
    for (int rep = 0; rep < 16; ++rep) {
        int e = tid + rep * 256;
        int d = e >> 6, l = e & 63;
        Cs[l * 72 + d] = f2b(Cb[e]);   // transposed: Cs[n=l][k=d]
    }
    __syncthreads();
    int quad = lane >> 4, mr = lane & 15;
    f32x4 acc[2][4] = {};
#pragma unroll
    for (int kk = 0; kk < 64; kk += 32) {
        bf16x8 a[2], bb[4];
#pragma unroll
        for (int i = 0; i < 2; i++) a[i] = *(const bf16x8*)&Qs[(w * 32 + i * 16 + mr) * 64 + kk + quad * 8];
#pragma unroll
        for (int j = 0; j < 4; j++) bb[j] = *(const bf16x8*)&Cs[(j * 16 + mr) * 72 + kk + quad * 8];
#pragma unroll
        for (int i = 0; i < 2; i++)
#pragma unroll
            for (int j = 0; j < 4; j++)
                acc[i][j] = __builtin_amdgcn_mfma_f32_16x16x32_bf16(a[i], bb[j], acc[i][j], 0, 0, 0);
    }
#pragma unroll
    for (int i = 0; i < 2; i++)
#pragma unroll
        for (int j = 0; j < 4; j++)
#pragma unroll
            for (int r = 0; r < 4; r++) {
                size_t row = row0 + w * 32 + i * 16 + quad * 4 + r;
                int col = h * 64 + j * 16 + mr;
                y[row * 1024 + col] = f2b(acc[i][j][r]);
            }
}

// ---------------- h_in = silu( LN(y)*sn_g+sn_b )*(1+scale)+shift ), bf16 in place ----------------
__global__ __launch_bounds__(256) void style_k(
    u16* __restrict__ y, const float* __restrict__ eo, const float* __restrict__ embb,
    const float* __restrict__ sng, const float* __restrict__ snb)
{
    int row = blockIdx.x, tid = threadIdx.x, b = row >> 12;
    u16* yr = y + (size_t)row * 1024;
    ushort4 u = *(const ushort4*)(yr + tid * 4);
    float vv[4] = { b2f(u.x), b2f(u.y), b2f(u.z), b2f(u.w) };
    float s = vv[0] + vv[1] + vv[2] + vv[3];
    float s2 = vv[0] * vv[0] + vv[1] * vv[1] + vv[2] * vv[2] + vv[3] * vv[3];
#pragma unroll
    for (int m = 32; m > 0; m >>= 1) { s += __shfl_xor(s, m, 64); s2 += __shfl_xor(s2, m, 64); }
    __shared__ float red[8];
    int w = tid >> 6, lane = tid & 63;
    if (lane == 0) { red[w] = s; red[4 + w] = s2; }
    __syncthreads();
    s = red[0] + red[1] + red[2] + red[3];
    s2 = red[4] + red[5] + red[6] + red[7];
    float mean = s * (1.f / 1024.f);
    float var = s2 * (1.f / 1024.f) - mean * mean;
    float rstd = rsqrtf(var + 1e-5f);
    int c = tid * 4;
    ushort4 o;
    u16* op = (u16*)&o;
#pragma unroll
    for (int i = 0; i < 4; i++) {
        int cc = c + i;
        float scale = eo[b * 2048 + cc] + embb[cc];
        float shift = eo[b * 2048 + 1024 + cc] + embb[1024 + cc];
        float hn = (vv[i] - mean) * rstd * sng[cc] + snb[cc];
        float hh = hn * (1.f + scale) + shift;
        op[i] = f2b(hh / (1.f + __expf(-hh)));
    }
    *(ushort4*)(yr + c) = o;
}

extern "C" void kernel_launch(void* const* d_in, const int* in_sizes, int n_in,
                              void* d_out, int out_size, void* d_ws, size_t ws_size,
                              hipStream_t stream)
{
    const float* x    = (const float*)d_in[0];
    const float* emb  = (const float*)d_in[1];
    const float* gate = (const float*)d_in[2];
    const float* ng   = (const float*)d_in[3];
    const float* nb   = (const float*)d_in[4];
    const float* Wq   = (const float*)d_in[5];
    const float* bq   = (const float*)d_in[6];
    const float* Wk   = (const float*)d_in[7];
    const float* bk   = (const float*)d_in[8];
    const float* Wv   = (const float*)d_in[9];
    const float* bv   = (const float*)d_in[10];
    const float* embW = (const float*)d_in[11];
    const float* embB = (const float*)d_in[12];
    const float* sng  = (const float*)d_in[13];
    const float* snb  = (const float*)d_in[14];
    const float* Wo   = (const float*)d_in[15];
    const float* ob   = (const float*)d_in[16];
    float* out = (float*)d_out;

    uint8_t* ws = (uint8_t*)d_ws;
    size_t off = 0;
    auto alloc = [&](size_t bytes) { void* p = ws + off; off += (bytes + 255) & ~(size_t)255; return p; };
    u16*   WqkvT   = (u16*)alloc(3072ull * 1024 * 2);    // 6 MB (qT | kT | vT) bf16
    u16*   WoT     = (u16*)alloc(1024ull * 1024 * 2);    // 2 MB bf16
    float* biasAll = (float*)alloc(4096 * 4);            // 16 KB
    // contiguous zero region: colsum | ctx | embout  (all sizes 256-aligned)
    float* colsum  = (float*)alloc(4096 * 4);            // 16 KB
    float* ctx     = (float*)alloc(64ull * 64 * 64 * 4); // 1 MB
    float* embout  = (float*)alloc(4ull * 2048 * 4);     // 32 KB
    u16*   XN      = (u16*)alloc(16384ull * 1024 * 2);   // 32 MB: xn -> y -> h_in
    u16*   BUF0    = (u16*)alloc(16384ull * 1024 * 2);   // 32 MB: Qsoft
    u16*   BUF1    = (u16*)alloc(16384ull * 1024 * 2);   // 32 MB: expK
    u16*   BUF2    = (u16*)alloc(16384ull * 1024 * 2);   // 32 MB: V
    // peak ws ~137 MB

    // 1. prep (transpose W, pack bias, zero colsum+ctx+embout = 1097728 B = 268 blocks)
    prep_k<<<4380, 256, 0, stream>>>(Wq, Wk, Wv, Wo, bq, bk, bv, ob, WqkvT, WoT, biasAll, colsum);
    // 2. LN
    ln_x<<<16384, 256, 0, stream>>>(x, ng, nb, XN);
    // 3. fused QKV GEMM (N=3072): Qsoft | expK + colsum | V
    gemm128<<<dim3(24, 128), 256, 0, stream>>>(XN, WqkvT, biasAll, 0,
                                               BUF0, BUF1, BUF2, colsum, nullptr, nullptr, nullptr);
    // 4. ctx = softmaxT(K)^T V
    ctx_k<<<dim3(8, 16, 4), 256, 0, stream>>>(BUF1, BUF2, colsum, ctx);
    // 5. emb_out
    embout_k<<<dim3(8, 8), 256, 0, stream>>>(emb, embW, embout);
    // 6. y = Qsoft @ ctx (into XN)
    y_k<<<dim3(32, 16, 4), 256, 0, stream>>>(BUF0, ctx, XN);
    // 7. stylization (in place on XN)
    style_k<<<16384, 256, 0, stream>>>(XN, embout, embB, sng, snb);
    // 8. out = x + gate * (h @ Wo + out_b)
    gemm128<<<dim3(8, 128), 256, 0, stream>>>(XN, WoT, biasAll + 3072, 2,
                                              nullptr, nullptr, nullptr, nullptr, out, x, gate);
}

// Round 6
// 465.239 us; speedup vs baseline: 1.3918x; 1.0799x over previous
//
#include <hip/hip_runtime.h>
#include <stdint.h>

typedef unsigned short u16;
typedef float f32x4 __attribute__((ext_vector_type(4)));
typedef __bf16 bf16x8 __attribute__((ext_vector_type(8)));

__device__ __forceinline__ float b2f(u16 u) {
    union { unsigned int i; float f; } w; w.i = ((unsigned int)u) << 16; return w.f;
}
__device__ __forceinline__ u16 f2b(float f) {
    union { float f; unsigned int i; } w; w.f = f;
    unsigned int r = w.i + 0x7fffu + ((w.i >> 16) & 1u);
    return (u16)(r >> 16);
}
__device__ __forceinline__ void gload16(const void* g, void* l) {
    __builtin_amdgcn_global_load_lds(
        (const __attribute__((address_space(1))) unsigned int*)g,
        (__attribute__((address_space(3))) unsigned int*)l, 16, 0, 0);
}

// ---------------- prep: transpose+cast 4 weights, pack biases, zero scratch ----------------
__global__ __launch_bounds__(256) void prep_k(
    const float* __restrict__ Wq, const float* __restrict__ Wk, const float* __restrict__ Wv,
    const float* __restrict__ Wo, const float* __restrict__ bq, const float* __restrict__ bk,
    const float* __restrict__ bv, const float* __restrict__ ob,
    u16* __restrict__ WqkvT, u16* __restrict__ WoT, float* __restrict__ biasAll,
    float* __restrict__ zeroBase)
{
    int bz = blockIdx.x, tid = threadIdx.x;
    if (bz < 4096) {
        int z = bz >> 10, rem = bz & 1023;
        const float* src = (z == 0) ? Wq : (z == 1) ? Wk : (z == 2) ? Wv : Wo;
        u16* dst = (z < 3) ? (WqkvT + (size_t)z * 1024 * 1024) : WoT;
        __shared__ u16 tile[32][33];
        int tx = tid & 31, ty = tid >> 5;  // 32 x 8
        int n0 = (rem & 31) * 32, k0 = (rem >> 5) * 32;
#pragma unroll
        for (int i = 0; i < 4; i++) tile[ty + 8 * i][tx] = f2b(src[(size_t)(k0 + ty + 8 * i) * 1024 + n0 + tx]);
        __syncthreads();
#pragma unroll
        for (int i = 0; i < 4; i++) dst[(size_t)(n0 + ty + 8 * i) * 1024 + k0 + tx] = tile[tx][ty + 8 * i];
    } else if (bz < 4112) {
        int i = (bz - 4096) * 256 + tid;
        float v;
        if (i < 1024) v = bq[i];
        else if (i < 2048) v = bk[i - 1024];
        else if (i < 3072) v = bv[i - 2048];
        else v = ob[i - 3072];
        biasAll[i] = v;
    } else {
        int e = (bz - 4112) * 256 + tid;           // float4 index
        ((float4*)zeroBase)[e] = make_float4(0.f, 0.f, 0.f, 0.f);
    }
}

// ---------------- LayerNorm(x fp32) -> xn (bf16), one row per block ----------------
__global__ __launch_bounds__(256) void ln_x(
    const float* __restrict__ x, const float* __restrict__ g, const float* __restrict__ bt,
    u16* __restrict__ xn)
{
    int row = blockIdx.x, tid = threadIdx.x;
    const float* xr = x + (size_t)row * 1024;
    float4 u = *(const float4*)(xr + tid * 4);
    float v0 = u.x, v1 = u.y, v2 = u.z, v3 = u.w;
    float s = v0 + v1 + v2 + v3;
    float s2 = v0 * v0 + v1 * v1 + v2 * v2 + v3 * v3;
#pragma unroll
    for (int m = 32; m > 0; m >>= 1) { s += __shfl_xor(s, m, 64); s2 += __shfl_xor(s2, m, 64); }
    __shared__ float red[8];
    int w = tid >> 6, lane = tid & 63;
    if (lane == 0) { red[w] = s; red[4 + w] = s2; }
    __syncthreads();
    s = red[0] + red[1] + red[2] + red[3];
    s2 = red[4] + red[5] + red[6] + red[7];
    float mean = s * (1.f / 1024.f);
    float var = s2 * (1.f / 1024.f) - mean * mean;
    float rstd = rsqrtf(var + 1e-5f);
    int c = tid * 4;
    float4 gg = *(const float4*)(g + c);
    float4 bb = *(const float4*)(bt + c);
    ushort4 o;
    o.x = f2b((v0 - mean) * rstd * gg.x + bb.x);
    o.y = f2b((v1 - mean) * rstd * gg.y + bb.y);
    o.z = f2b((v2 - mean) * rstd * gg.z + bb.z);
    o.w = f2b((v3 - mean) * rstd * gg.w + bb.w);
    *(ushort4*)(xn + (size_t)row * 1024 + c) = o;
}

// ---------------- 128x128 MFMA GEMM, K=1024, gload16 staging, XCD swizzle, XOR bank-swizzle ----
// LDS layout: tile[row][cb] = global[row][cb ^ (row&7)]  (cb = 16B column block)
// mode 0: fused QKV: col<1024 Q+softmax -> Qb; <2048 K -> exp + colsum atomics; else V -> Vb
// mode 2: out = Xf + gate*(A@B+bias) -> Cf (fp32)
__global__ __launch_bounds__(256) void gemm128(
    const u16* __restrict__ A, const u16* __restrict__ Bt, const float* __restrict__ bias,
    int mode, u16* __restrict__ Qb, u16* __restrict__ Kb, u16* __restrict__ Vb,
    float* __restrict__ colsum, float* __restrict__ Cf,
    const float* __restrict__ Xf, const float* __restrict__ gate)
{
    const int K = 1024;
    __shared__ __align__(16) u16 As[128 * 64];
    __shared__ __align__(16) u16 Bs[128 * 64];
    int tid = threadIdx.x, lane = tid & 63, w = tid >> 6;
    int wm = w >> 1, wn = w & 1;
    // XCD swizzle: each XCD owns 16 row-tiles (4MB A), walks cols outer.
    int NB = gridDim.x;
    int lid = blockIdx.y * NB + blockIdx.x;
    int xcd = lid & 7;
    int i_ = lid >> 3;
    int rowLocal = i_ & 15;
    int colIdx = i_ >> 4;
    size_t rowbase = (size_t)(xcd * 16 + rowLocal) * 128;
    size_t colbase = (size_t)colIdx * 128;
    const u16* Ab = A + rowbase * K;
    const u16* Bb = Bt + colbase * K;
    f32x4 acc[4][4] = {};
    int quad = lane >> 4, mr = lane & 15;
    // staging source column (bank-swizzled): lane lands at LDS[r][lane&7]; feed global[r][(lane&7)^(r&7)]
    int scol = (((lane & 7) ^ ((lane >> 3) & 7))) * 8;
    int srow = lane >> 3;
    int swA = mr & 7;
    for (int k0 = 0; k0 < K; k0 += 64) {
#pragma unroll
        for (int j = 0; j < 4; j++) {
            int r = w * 32 + j * 8 + srow;
            gload16(Ab + (size_t)r * K + k0 + scol, &As[(w * 32 + j * 8) * 64]);
            gload16(Bb + (size_t)r * K + k0 + scol, &Bs[(w * 32 + j * 8) * 64]);
        }
        __syncthreads();
#pragma unroll
        for (int kk = 0; kk < 64; kk += 32) {
            bf16x8 a[4], bf[4];
#pragma unroll
            for (int i = 0; i < 4; i++)
                a[i] = *(const bf16x8*)&As[(wm * 64 + i * 16 + mr) * 64 + ((((kk >> 3) + quad) ^ swA) * 8)];
#pragma unroll
            for (int j = 0; j < 4; j++)
                bf[j] = *(const bf16x8*)&Bs[(wn * 64 + j * 16 + mr) * 64 + ((((kk >> 3) + quad) ^ swA) * 8)];
#pragma unroll
            for (int i = 0; i < 4; i++)
#pragma unroll
                for (int j = 0; j < 4; j++)
                    acc[i][j] = __builtin_amdgcn_mfma_f32_16x16x32_bf16(a[i], bf[j], acc[i][j], 0, 0, 0);
        }
        __syncthreads();
    }
    int colj[4]; float bj[4];
#pragma unroll
    for (int j = 0; j < 4; j++) { colj[j] = (int)colbase + wn * 64 + j * 16 + mr; bj[j] = bias[colj[j]]; }
    int creg = (int)colbase + wn * 64;   // wave-uniform region start
    if (mode == 0) {
        if (creg < 1024) {
            // Q + feature softmax over this wave's 64-col head span
#pragma unroll
            for (int i = 0; i < 4; i++) {
#pragma unroll
                for (int r = 0; r < 4; r++) {
                    size_t row = rowbase + wm * 64 + i * 16 + quad * 4 + r;
                    float v[4], m = -1e30f, ss = 0.f;
#pragma unroll
                    for (int j = 0; j < 4; j++) { v[j] = acc[i][j][r] + bj[j]; m = fmaxf(m, v[j]); }
#pragma unroll
                    for (int s = 1; s < 16; s <<= 1) m = fmaxf(m, __shfl_xor(m, s, 64));
#pragma unroll
                    for (int j = 0; j < 4; j++) { v[j] = __expf(v[j] - m); ss += v[j]; }
#pragma unroll
                    for (int s = 1; s < 16; s <<= 1) ss += __shfl_xor(ss, s, 64);
                    float inv = 1.f / ss;
#pragma unroll
                    for (int j = 0; j < 4; j++) Qb[row * 1024 + colj[j]] = f2b(v[j] * inv);
                }
            }
        } else if (creg < 2048) {
            // K: store exp(k) bf16; accumulate per-column exp-sums -> colsum
            int b_ = (int)(rowbase >> 12);
            float csum[4] = {};
#pragma unroll
            for (int j = 0; j < 4; j++) {
#pragma unroll
                for (int i = 0; i < 4; i++) {
#pragma unroll
                    for (int r = 0; r < 4; r++) {
                        size_t row = rowbase + wm * 64 + i * 16 + quad * 4 + r;
                        float e = __expf(acc[i][j][r] + bj[j]);
                        Kb[row * 1024 + (colj[j] - 1024)] = f2b(e);
                        csum[j] += e;
                    }
                }
            }
#pragma unroll
            for (int j = 0; j < 4; j++) {
                csum[j] += __shfl_xor(csum[j], 16, 64);
                csum[j] += __shfl_xor(csum[j], 32, 64);
                if (quad == 0) atomicAdd(&colsum[b_ * 1024 + (colj[j] - 1024)], csum[j]);
            }
        } else {
            // V: plain store
#pragma unroll
            for (int j = 0; j < 4; j++) {
#pragma unroll
                for (int i = 0; i < 4; i++) {
#pragma unroll
                    for (int r = 0; r < 4; r++) {
                        size_t row = rowbase + wm * 64 + i * 16 + quad * 4 + r;
                        Vb[row * 1024 + (colj[j] - 2048)] = f2b(acc[i][j][r] + bj[j]);
                    }
                }
            }
        }
        return;
    }
    // mode 2: out = Xf + gate * (A@B + bias)
    int b_ = (int)(rowbase >> 12);
#pragma unroll
    for (int j = 0; j < 4; j++) {
        float gv = gate[b_ * 1024 + colj[j]];
#pragma unroll
        for (int i = 0; i < 4; i++) {
#pragma unroll
            for (int r = 0; r < 4; r++) {
                size_t row = rowbase + wm * 64 + i * 16 + quad * 4 + r;
                float v = acc[i][j][r] + bj[j];
                Cf[row * 1024 + colj[j]] = Xf[row * 1024 + colj[j]] + gv * v;
            }
        }
    }
}

// ---------------- ctx[b,h] = (expK * inv_colsum)^T V ----------------
__global__ __launch_bounds__(256) void ctx_k(
    const u16* __restrict__ kbuf, const u16* __restrict__ vbuf,
    const float* __restrict__ colsum, float* __restrict__ ctx)
{
    int ch = blockIdx.x, h = blockIdx.y, b = blockIdx.z;
    __shared__ __align__(16) float Es[16][64];
    __shared__ __align__(16) float Vs[16][64];
    int tid = threadIdx.x;
    int td = tid >> 4, tl = tid & 15;
    float invc = 1.f / colsum[b * 1024 + h * 64 + (tid & 63)];
    float acc[4][4] = {};
    size_t rowbase = (size_t)b * 4096 + ch * 512;
    for (int g = 0; g < 32; ++g) {
#pragma unroll
        for (int rep = 0; rep < 4; ++rep) {
            int e = tid + rep * 256;
            int r = e >> 6, cc = e & 63;
            size_t base = (rowbase + g * 16 + r) * 1024 + h * 64 + cc;
            Es[r][cc] = b2f(kbuf[base]) * invc;   // kbuf holds exp(k)
            Vs[r][cc] = b2f(vbuf[base]);
        }
        __syncthreads();
#pragma unroll
        for (int n = 0; n < 16; n++) {
            f32x4 e4 = *(const f32x4*)&Es[n][td * 4];
            f32x4 v4 = *(const f32x4*)&Vs[n][tl * 4];
#pragma unroll
            for (int i = 0; i < 4; i++)
#pragma unroll
                for (int j = 0; j < 4; j++) acc[i][j] += e4[i] * v4[j];
        }
        __syncthreads();
    }
    float* cb = ctx + (size_t)(b * 16 + h) * 4096;
#pragma unroll
    for (int i = 0; i < 4; i++)
#pragma unroll
        for (int j = 0; j < 4; j++)
            atomicAdd(&cb[(td * 4 + i) * 64 + tl * 4 + j], acc[i][j]);
}

// ---------------- emb_out = silu(emb) @ emb_W (fp32, atomic over k chunks) ----------------
__global__ __launch_bounds__(256) void embout_k(
    const float* __restrict__ emb, const float* __restrict__ embW, float* __restrict__ eo)
{
    int cb = blockIdx.x, kc = blockIdx.y;
    __shared__ float semb[512];
    int tid = threadIdx.x;
#pragma unroll
    for (int i = 0; i < 2; i++) {
        int e = tid + i * 256;
        int b = e >> 7, kk = e & 127;
        float xv = emb[b * 1024 + kc * 128 + kk];
        semb[e] = xv / (1.f + __expf(-xv));
    }
    __syncthreads();
    int o = cb * 256 + tid;
    float a0 = 0, a1 = 0, a2 = 0, a3 = 0;
    for (int kk = 0; kk < 128; kk++) {
        float wv = embW[(size_t)(kc * 128 + kk) * 2048 + o];
        a0 += semb[kk] * wv; a1 += semb[128 + kk] * wv;
        a2 += semb[256 + kk] * wv; a3 += semb[384 + kk] * wv;
    }
    atomicAdd(&eo[o], a0);
    atomicAdd(&eo[2048 + o], a1);
    atomicAdd(&eo[4096 + o], a2);
    atomicAdd(&eo[6144 + o], a3);
}

// ---------------- y = q_soft @ ctx per head (MFMA, K=64), XOR bank-swizzled Qs ----------------
__global__ __launch_bounds__(256) void y_k(
    const u16* __restrict__ q, const float* __restrict__ ctx, u16* __restrict__ y)
{
    int mc = blockIdx.x, h = blockIdx.y, b = blockIdx.z;
    __shared__ __align__(16) u16 Qs[128 * 64];
    __shared__ __align__(16) u16 Cs[64 * 72];
    int tid = threadIdx.x, lane = tid & 63, w = tid >> 6;
    size_t row0 = (size_t)b * 4096 + (size_t)mc * 128;
    const u16* Qb = q + row0 * 1024 + h * 64;
    int sr = tid >> 3, g_ = tid & 7;
    int scb = (g_ ^ (sr & 7)) * 8;   // LDS col block (swizzled); global col = g_*8
#pragma unroll
    for (int p = 0; p < 4; p++) {
        int r = p * 32 + sr;
        *(uint4*)&Qs[r * 64 + scb] = *(const uint4*)&Qb[(size_t)r * 1024 + g_ * 8];
    }
    const float* Cb = ctx + (size_t)(b * 16 + h) * 4096;
#pragma unroll
    for (int rep = 0; rep < 16; ++rep) {
        int e = tid + rep * 256;
        int d = e >> 6, l = e & 63;
        Cs[l * 72 + d] = f2b(Cb[e]);   // transposed: Cs[n=l][k=d]
    }
    __syncthreads();
    int quad = lane >> 4, mr = lane & 15;
    int swA = mr & 7;
    f32x4 acc[2][4] = {};
#pragma unroll
    for (int kk = 0; kk < 64; kk += 32) {
        bf16x8 a[2], bb[4];
#pragma unroll
        for (int i = 0; i < 2; i++)
            a[i] = *(const bf16x8*)&Qs[(w * 32 + i * 16 + mr) * 64 + ((((kk >> 3) + quad) ^ swA) * 8)];
#pragma unroll
        for (int j = 0; j < 4; j++) bb[j] = *(const bf16x8*)&Cs[(j * 16 + mr) * 72 + kk + quad * 8];
#pragma unroll
        for (int i = 0; i < 2; i++)
#pragma unroll
            for (int j = 0; j < 4; j++)
                acc[i][j] = __builtin_amdgcn_mfma_f32_16x16x32_bf16(a[i], bb[j], acc[i][j], 0, 0, 0);
    }
#pragma unroll
    for (int i = 0; i < 2; i++)
#pragma unroll
        for (int j = 0; j < 4; j++)
#pragma unroll
            for (int r = 0; r < 4; r++) {
                size_t row = row0 + w * 32 + i * 16 + quad * 4 + r;
                int col = h * 64 + j * 16 + mr;
                y[row * 1024 + col] = f2b(acc[i][j][r]);
            }
}

// ---------------- h_in = silu( LN(y)*sn_g+sn_b )*(1+scale)+shift ), bf16 in place ----------------
__global__ __launch_bounds__(256) void style_k(
    u16* __restrict__ y, const float* __restrict__ eo, const float* __restrict__ embb,
    const float* __restrict__ sng, const float* __restrict__ snb)
{
    int row = blockIdx.x, tid = threadIdx.x, b = row >> 12;
    u16* yr = y + (size_t)row * 1024;
    ushort4 u = *(const ushort4*)(yr + tid * 4);
    float vv[4] = { b2f(u.x), b2f(u.y), b2f(u.z), b2f(u.w) };
    float s = vv[0] + vv[1] + vv[2] + vv[3];
    float s2 = vv[0] * vv[0] + vv[1] * vv[1] + vv[2] * vv[2] + vv[3] * vv[3];
#pragma unroll
    for (int m = 32; m > 0; m >>= 1) { s += __shfl_xor(s, m, 64); s2 += __shfl_xor(s2, m, 64); }
    __shared__ float red[8];
    int w = tid >> 6, lane = tid & 63;
    if (lane == 0) { red[w] = s; red[4 + w] = s2; }
    __syncthreads();
    s = red[0] + red[1] + red[2] + red[3];
    s2 = red[4] + red[5] + red[6] + red[7];
    float mean = s * (1.f / 1024.f);
    float var = s2 * (1.f / 1024.f) - mean * mean;
    float rstd = rsqrtf(var + 1e-5f);
    int c = tid * 4;
    ushort4 o;
    u16* op = (u16*)&o;
#pragma unroll
    for (int i = 0; i < 4; i++) {
        int cc = c + i;
        float scale = eo[b * 2048 + cc] + embb[cc];
        float shift = eo[b * 2048 + 1024 + cc] + embb[1024 + cc];
        float hn = (vv[i] - mean) * rstd * sng[cc] + snb[cc];
        float hh = hn * (1.f + scale) + shift;
        op[i] = f2b(hh / (1.f + __expf(-hh)));
    }
    *(ushort4*)(yr + c) = o;
}

extern "C" void kernel_launch(void* const* d_in, const int* in_sizes, int n_in,
                              void* d_out, int out_size, void* d_ws, size_t ws_size,
                              hipStream_t stream)
{
    const float* x    = (const float*)d_in[0];
    const float* emb  = (const float*)d_in[1];
    const float* gate = (const float*)d_in[2];
    const float* ng   = (const float*)d_in[3];
    const float* nb   = (const float*)d_in[4];
    const float* Wq   = (const float*)d_in[5];
    const float* bq   = (const float*)d_in[6];
    const float* Wk   = (const float*)d_in[7];
    const float* bk   = (const float*)d_in[8];
    const float* Wv   = (const float*)d_in[9];
    const float* bv   = (const float*)d_in[10];
    const float* embW = (const float*)d_in[11];
    const float* embB = (const float*)d_in[12];
    const float* sng  = (const float*)d_in[13];
    const float* snb  = (const float*)d_in[14];
    const float* Wo   = (const float*)d_in[15];
    const float* ob   = (const float*)d_in[16];
    float* out = (float*)d_out;

    uint8_t* ws = (uint8_t*)d_ws;
    size_t off = 0;
    auto alloc = [&](size_t bytes) { void* p = ws + off; off += (bytes + 255) & ~(size_t)255; return p; };
    u16*   WqkvT   = (u16*)alloc(3072ull * 1024 * 2);    // 6 MB (qT | kT | vT) bf16
    u16*   WoT     = (u16*)alloc(1024ull * 1024 * 2);    // 2 MB bf16
    float* biasAll = (float*)alloc(4096 * 4);            // 16 KB
    // contiguous zero region: colsum | ctx | embout
    float* colsum  = (float*)alloc(4096 * 4);            // 16 KB
    float* ctx     = (float*)alloc(64ull * 64 * 64 * 4); // 1 MB
    float* embout  = (float*)alloc(4ull * 2048 * 4);     // 32 KB
    u16*   XN      = (u16*)alloc(16384ull * 1024 * 2);   // 32 MB: xn -> y -> h_in
    u16*   BUF0    = (u16*)alloc(16384ull * 1024 * 2);   // 32 MB: Qsoft
    u16*   BUF1    = (u16*)alloc(16384ull * 1024 * 2);   // 32 MB: expK
    u16*   BUF2    = (u16*)alloc(16384ull * 1024 * 2);   // 32 MB: V

    prep_k<<<4380, 256, 0, stream>>>(Wq, Wk, Wv, Wo, bq, bk, bv, ob, WqkvT, WoT, biasAll, colsum);
    ln_x<<<16384, 256, 0, stream>>>(x, ng, nb, XN);
    gemm128<<<dim3(24, 128), 256, 0, stream>>>(XN, WqkvT, biasAll, 0,
                                               BUF0, BUF1, BUF2, colsum, nullptr, nullptr, nullptr);
    ctx_k<<<dim3(8, 16, 4), 256, 0, stream>>>(BUF1, BUF2, colsum, ctx);
    embout_k<<<dim3(8, 8), 256, 0, stream>>>(emb, embW, embout);
    y_k<<<dim3(32, 16, 4), 256, 0, stream>>>(BUF0, ctx, XN);
    style_k<<<16384, 256, 0, stream>>>(XN, embout, embB, sng, snb);
    gemm128<<<dim3(8, 128), 256, 0, stream>>>(XN, WoT, biasAll + 3072, 2,
                                              nullptr, nullptr, nullptr, nullptr, out, x, gate);
}